// Round 2
// baseline (12.342 us; speedup 1.0000x reference)
//
#include <hip/hip_runtime.h>
#include <hip/hip_bf16.h>

// Embedding gather: out[b,s,:] = table[x[b,s], :]
// x: [4,2048] int32 (8192 tokens), table: [32000,128] f32, out: [8192,128] f32.
// 2 float4 units per thread from two distinct tokens -> 2 independent
// index->row load chains per thread (2x MLP vs round-1 kernel).

__global__ __launch_bounds__(256) void embedding_gather_kernel(
    const int* __restrict__ x,
    const float4* __restrict__ table,   // [32000][32] float4
    float4* __restrict__ out,           // [8192][32] float4
    int half_units)                     // total float4 units / 2
{
    int gid = blockIdx.x * blockDim.x + threadIdx.x;

    int u0 = gid;               // first half of the output
    int u1 = gid + half_units;  // second half

    int t0 = u0 >> 5, e0 = u0 & 31;
    int t1 = u1 >> 5, e1 = u1 & 31;

    // Independent index loads (both issue before either row gather).
    int r0 = x[t0];
    int r1 = x[t1];

    float4 v0 = table[(size_t)r0 * 32 + e0];
    float4 v1 = table[(size_t)r1 * 32 + e1];

    out[(size_t)t0 * 32 + e0] = v0;
    out[(size_t)t1 * 32 + e1] = v1;
}

extern "C" void kernel_launch(void* const* d_in, const int* in_sizes, int n_in,
                              void* d_out, int out_size, void* d_ws, size_t ws_size,
                              hipStream_t stream) {
    const int*    x     = (const int*)d_in[0];
    const float4* table = (const float4*)d_in[1];
    float4*       out   = (float4*)d_out;

    const int n_tokens   = in_sizes[0];          // 8192
    const int total      = n_tokens * 32;        // float4 units (262144)
    const int half_units = total / 2;            // 131072
    const int block      = 256;
    const int grid       = half_units / block;   // 512 blocks

    embedding_gather_kernel<<<grid, block, 0, stream>>>(x, table, out, half_units);
}

// Round 4
// 9.997 us; speedup vs baseline: 1.2346x; 1.2346x over previous
//
#include <hip/hip_runtime.h>
#include <hip/hip_bf16.h>

// Embedding gather: out[b,s,:] = table[x[b,s], :]
// x: [4,2048] int32 (8192 tokens), table: [32000,128] f32, out: [8192,128] f32.
// One 16B unit per thread; 32 threads per token row (128 f32 = 32 x f32x4).
// R4: R1 structure (best so far, 9.74us) + nontemporal stores via native
// clang vector type (__builtin_nontemporal_store rejects HIP_vector_type).

typedef float f32x4 __attribute__((ext_vector_type(4)));

__global__ __launch_bounds__(256) void embedding_gather_kernel(
    const int* __restrict__ x,
    const f32x4* __restrict__ table,    // [32000][32] f32x4
    f32x4* __restrict__ out,            // [8192][32] f32x4
    int n_tokens)
{
    int gid = blockIdx.x * blockDim.x + threadIdx.x;   // one f32x4 per thread
    int token = gid >> 5;          // gid / 32
    int elem  = gid & 31;          // gid % 32
    if (token < n_tokens) {
        int row = x[token];
        f32x4 v = table[(size_t)row * 32 + elem];
        __builtin_nontemporal_store(v, &out[(size_t)token * 32 + elem]);
    }
}

extern "C" void kernel_launch(void* const* d_in, const int* in_sizes, int n_in,
                              void* d_out, int out_size, void* d_ws, size_t ws_size,
                              hipStream_t stream) {
    const int*   x     = (const int*)d_in[0];
    const f32x4* table = (const f32x4*)d_in[1];
    f32x4*       out   = (f32x4*)d_out;

    const int n_tokens = in_sizes[0];            // 8192
    const int total    = n_tokens * 32;          // f32x4 units
    const int block    = 256;
    const int grid     = (total + block - 1) / block;   // 1024

    embedding_gather_kernel<<<grid, block, 0, stream>>>(x, table, out, n_tokens);
}